// Round 1
// baseline (658.473 us; speedup 1.0000x reference)
//
#include <hip/hip_runtime.h>
#include <math.h>

// Problem constants (MixtureLowRankRNN)
#define HIDDEN_ 1024
#define RANK_ 4
#define INPUT_ 16
#define T_ 1024
#define BATCH_ 32

#define NTHREADS_ 256
#define NWAVES_ (NTHREADS_ / 64)     // 4 waves, one per SIMD
#define EPT_ (HIDDEN_ / NTHREADS_)   // 4 h-elements per thread

__device__ __forceinline__ float fast_exp2(float x) {
#if defined(__has_builtin)
#if __has_builtin(__builtin_amdgcn_exp2f)
    return __builtin_amdgcn_exp2f(x);
#else
    return exp2f(x);
#endif
#else
    return exp2f(x);
#endif
}

__device__ __forceinline__ float fast_rcp(float x) {
#if defined(__has_builtin)
#if __has_builtin(__builtin_amdgcn_rcpf)
    return __builtin_amdgcn_rcpf(x);
#else
    return 1.0f / x;
#endif
#else
    return 1.0f / x;
#endif
}

// tanh(x) = 1 - 2/(exp(2x)+1); exp(2x) = 2^(2*log2(e)*x).
__device__ __forceinline__ float tanh_fast(float x) {
    float e = fast_exp2(x * 2.885390081777926815f); // 2*log2(e)
    return fmaf(-2.0f, fast_rcp(e + 1.0f), 1.0f);
}

// One DPP reduce step: v += dpp_mov(v, ctrl) with old=0, bound_ctrl=1
#define DPP_ADD(v, ctrl)                                                          \
    do {                                                                          \
        int _t = __builtin_amdgcn_update_dpp(0, __float_as_int(v), (ctrl), 0xf,   \
                                             0xf, true);                          \
        (v) += __int_as_float(_t);                                                \
    } while (0)

// One block per batch element; h entirely in registers (4 elems/thread).
// Output identity: pinv([m|I]) @ [m|I] = I_20, so
//   y_t = 0.9*y_{t-1} + [krec*s_t ; kin*x_t],  s_t = n^T tanh(h_{t-1}).
//
// This revision:
//  - weights PINNED in VGPRs (asm pins + launch_bounds(.,1)) -> no scratch thrash
//  - raw s_barrier with lgkmcnt-only wait -> no per-step vmcnt(0) drain
//  - x loads forced to VMEM (opaque vzero index) + 1-step register prefetch
//  - ax = I@x precomputed between part[] ds_read issue and consumption
__global__ __launch_bounds__(NTHREADS_, 1) void rnn_scan_kernel(
    const float* __restrict__ x,     // [B, T, 16]
    const float* __restrict__ m,     // [H, 4]
    const float* __restrict__ n,     // [H, 4]
    const float* __restrict__ imat,  // [H, 16]
    float* __restrict__ out)         // [B, T, 20]
{
    const int b    = blockIdx.x;
    const int tid  = threadIdx.x;
    const int wave = tid >> 6;
    const int lane = tid & 63;

    const float kd   = 0.9f;                      // 1 - ALPHA
    const float krec = 0.1f * (500.0f / 1024.0f); // ALPHA * BASE_SCALE / HIDDEN
    const float kin  = 0.1f;                      // ALPHA

    float h[EPT_];
    float mrs[EPT_][RANK_];    // krec * m row
    float nr[EPT_][RANK_];
    float Irs[EPT_][INPUT_];   // kin * I row

#pragma unroll
    for (int j = 0; j < EPT_; ++j) {
        const int hidx = tid * EPT_ + j;
        h[j] = 0.0f;
        const float4 mv = *(const float4*)(m + hidx * RANK_);
        mrs[j][0] = krec * mv.x; mrs[j][1] = krec * mv.y;
        mrs[j][2] = krec * mv.z; mrs[j][3] = krec * mv.w;
        const float4 nv = *(const float4*)(n + hidx * RANK_);
        nr[j][0] = nv.x; nr[j][1] = nv.y; nr[j][2] = nv.z; nr[j][3] = nv.w;
#pragma unroll
        for (int q = 0; q < 4; ++q) {
            const float4 iv = *(const float4*)(imat + hidx * INPUT_ + q * 4);
            Irs[j][q*4+0] = kin * iv.x; Irs[j][q*4+1] = kin * iv.y;
            Irs[j][q*4+2] = kin * iv.z; Irs[j][q*4+3] = kin * iv.w;
        }
    }

    // Pin all weight arrays into VGPRs: opaque asm defs prevent the compiler
    // from spilling to scratch or rematerializing from global each step.
    // (VGPR_Count=68 in the previous build proved Irs never lived in regs.)
#pragma unroll
    for (int j = 0; j < EPT_; ++j) {
#pragma unroll
        for (int i = 0; i < INPUT_; ++i) asm volatile("" : "+v"(Irs[j][i]));
#pragma unroll
        for (int r = 0; r < RANK_; ++r) {
            asm volatile("" : "+v"(mrs[j][r]));
            asm volatile("" : "+v"(nr[j][r]));
        }
    }

    // parity double-buffer -> single barrier per step
    __shared__ float4 part[2][NWAVES_];

    // Opaque zero in a VGPR: forces x loads to be vector VMEM loads (vmcnt),
    // never scalarized to s_load (lgkmcnt) -- our per-step lgkmcnt(0) wait
    // must only cover the LDS ops, so prefetched x stays in flight.
    int vzero;
    asm volatile("v_mov_b32 %0, 0" : "=v"(vzero));

    const float* xb = x + (size_t)b * T_ * INPUT_;
    float* ob = out + (size_t)b * T_ * (RANK_ + INPUT_);

    float y = 0.0f;  // output accumulator (tid < 20)
    const bool is_xy = (tid >= 4 && tid < 20);
    float xy = is_xy ? xb[vzero + (tid - 4)] : 0.0f;

    // preload x[0] into registers
    float xr[INPUT_];
    {
        const float4* xp = (const float4*)xb;
#pragma unroll
        for (int q = 0; q < 4; ++q) {
            float4 v = xp[vzero + q];
            xr[q*4+0] = v.x; xr[q*4+1] = v.y; xr[q*4+2] = v.z; xr[q*4+3] = v.w;
        }
    }

#pragma unroll 2
    for (int t = 0; t < T_; ++t) {
        // --- tanh(h) + rank partials + wave DPP reduce (VALU only) ---
        float th[EPT_];
#pragma unroll
        for (int j = 0; j < EPT_; ++j) th[j] = tanh_fast(h[j]);

        float p0 = th[0] * nr[0][0], p1 = th[0] * nr[0][1];
        float p2 = th[0] * nr[0][2], p3 = th[0] * nr[0][3];
#pragma unroll
        for (int j = 1; j < EPT_; ++j) {
            p0 = fmaf(th[j], nr[j][0], p0);
            p1 = fmaf(th[j], nr[j][1], p1);
            p2 = fmaf(th[j], nr[j][2], p2);
            p3 = fmaf(th[j], nr[j][3], p3);
        }

        DPP_ADD(p0, 0x111); DPP_ADD(p1, 0x111); DPP_ADD(p2, 0x111); DPP_ADD(p3, 0x111);
        DPP_ADD(p0, 0x112); DPP_ADD(p1, 0x112); DPP_ADD(p2, 0x112); DPP_ADD(p3, 0x112);
        DPP_ADD(p0, 0x114); DPP_ADD(p1, 0x114); DPP_ADD(p2, 0x114); DPP_ADD(p3, 0x114);
        DPP_ADD(p0, 0x118); DPP_ADD(p1, 0x118); DPP_ADD(p2, 0x118); DPP_ADD(p3, 0x118);
        DPP_ADD(p0, 0x142); DPP_ADD(p1, 0x142); DPP_ADD(p2, 0x142); DPP_ADD(p3, 0x142);
        DPP_ADD(p0, 0x143); DPP_ADD(p1, 0x143); DPP_ADD(p2, 0x143); DPP_ADD(p3, 0x143);

        if (lane == 63) part[t & 1][wave] = make_float4(p0, p1, p2, p3);

        // Raw barrier: LDS-visibility wait ONLY (no vmcnt drain — x loads and
        // y stores stay in flight across steps).
        asm volatile("s_waitcnt lgkmcnt(0)\n\ts_barrier" ::: "memory");

        // --- issue cross-wave partial reads (ds_read, ~120cy) ---
        const float4 q0 = part[t & 1][0];
        const float4 q1 = part[t & 1][1];
        const float4 q2 = part[t & 1][2];
        const float4 q3 = part[t & 1][3];

        // --- issue next-step x prefetch (VMEM, consumed next iteration) ---
        const int tn = (t + 1 < T_) ? (t + 1) : t;   // clamp; value unused at t=T-1
        const float4* xp = (const float4*)(xb + tn * INPUT_);
        float4 xv0 = xp[vzero + 0];
        float4 xv1 = xp[vzero + 1];
        float4 xv2 = xp[vzero + 2];
        float4 xv3 = xp[vzero + 3];
        float xy_nxt = 0.0f;
        if (is_xy) xy_nxt = xb[tn * INPUT_ + vzero + (tid - 4)];

        // --- ax = (kin*I) @ x_t : independent of part[] -> fills ds_read wait ---
        float ax[EPT_];
#pragma unroll
        for (int j = 0; j < EPT_; ++j) {
            float a = xr[0] * Irs[j][0];
            float c = xr[1] * Irs[j][1];
#pragma unroll
            for (int i = 2; i < INPUT_; i += 2) {
                a = fmaf(xr[i],     Irs[j][i],     a);
                c = fmaf(xr[i + 1], Irs[j][i + 1], c);
            }
            ax[j] = a + c;
        }

        // --- combine partials -> s, then short s->h chain (5 FMAs) ---
        const float s0 = (q0.x + q1.x) + (q2.x + q3.x);
        const float s1 = (q0.y + q1.y) + (q2.y + q3.y);
        const float s2 = (q0.z + q1.z) + (q2.z + q3.z);
        const float s3 = (q0.w + q1.w) + (q2.w + q3.w);

#pragma unroll
        for (int j = 0; j < EPT_; ++j) {
            float a = fmaf(s0, mrs[j][0], ax[j]);
            a = fmaf(s1, mrs[j][1], a);
            a = fmaf(s2, mrs[j][2], a);
            a = fmaf(s3, mrs[j][3], a);
            h[j] = fmaf(kd, h[j], a);
        }

        // --- y_t = kd*y_{t-1} + [krec*s ; kin*x_t]  (lanes 0..19 of wave 0) ---
        if (tid < 20) {
            float drive;
            if (tid < 4) {
                float sv = (tid == 0) ? s0 : (tid == 1) ? s1 : (tid == 2) ? s2 : s3;
                drive = krec * sv;
            } else {
                drive = kin * xy;
            }
            y = fmaf(kd, y, drive);
            ob[t * 20 + tid] = y;   // fire-and-forget: never drained in-loop
        }

        // --- rotate prefetched x into current (SSA renames under unroll 2) ---
        xr[0]  = xv0.x; xr[1]  = xv0.y; xr[2]  = xv0.z; xr[3]  = xv0.w;
        xr[4]  = xv1.x; xr[5]  = xv1.y; xr[6]  = xv1.z; xr[7]  = xv1.w;
        xr[8]  = xv2.x; xr[9]  = xv2.y; xr[10] = xv2.z; xr[11] = xv2.w;
        xr[12] = xv3.x; xr[13] = xv3.y; xr[14] = xv3.z; xr[15] = xv3.w;
        xy = xy_nxt;
    }
}

extern "C" void kernel_launch(void* const* d_in, const int* in_sizes, int n_in,
                              void* d_out, int out_size, void* d_ws, size_t ws_size,
                              hipStream_t stream) {
    const float* x    = (const float*)d_in[0];
    const float* m    = (const float*)d_in[1];
    const float* n    = (const float*)d_in[2];
    const float* imat = (const float*)d_in[3];
    float* out = (float*)d_out;

    rnn_scan_kernel<<<dim3(BATCH_), dim3(NTHREADS_), 0, stream>>>(x, m, n, imat, out);
}

// Round 2
// 647.033 us; speedup vs baseline: 1.0177x; 1.0177x over previous
//
#include <hip/hip_runtime.h>
#include <math.h>

// Problem constants (MixtureLowRankRNN)
#define HIDDEN_ 1024
#define RANK_ 4
#define INPUT_ 16
#define T_ 1024
#define BATCH_ 32

#define NTHREADS_ 256
#define NWAVES_ (NTHREADS_ / 64)     // 4 waves, one per SIMD
#define EPT_ (HIDDEN_ / NTHREADS_)   // 4 h-elements per thread
#define CH_ 64                       // x-steps per LDS-staged chunk (64*64B = 4KB)
#define NCH_ (T_ / CH_)              // 16 chunks

typedef float f32x4 __attribute__((ext_vector_type(4)));

__device__ __forceinline__ float fast_exp2(float x) {
#if defined(__has_builtin)
#if __has_builtin(__builtin_amdgcn_exp2f)
    return __builtin_amdgcn_exp2f(x);
#else
    return exp2f(x);
#endif
#else
    return exp2f(x);
#endif
}

__device__ __forceinline__ float fast_rcp(float x) {
#if defined(__has_builtin)
#if __has_builtin(__builtin_amdgcn_rcpf)
    return __builtin_amdgcn_rcpf(x);
#else
    return 1.0f / x;
#endif
#else
    return 1.0f / x;
#endif
}

// tanh(x) = 1 - 2/(exp(2x)+1); exp(2x) = 2^(2*log2(e)*x).
__device__ __forceinline__ float tanh_fast(float x) {
    float e = fast_exp2(x * 2.885390081777926815f); // 2*log2(e)
    return fmaf(-2.0f, fast_rcp(e + 1.0f), 1.0f);
}

// One DPP reduce step: v += dpp_mov(v, ctrl) with old=0, bound_ctrl=1
#define DPP_ADD(v, ctrl)                                                          \
    do {                                                                          \
        int _t = __builtin_amdgcn_update_dpp(0, __float_as_int(v), (ctrl), 0xf,   \
                                             0xf, true);                          \
        (v) += __int_as_float(_t);                                                \
    } while (0)

// Opaque 16B global load: result is an asm output => compiler CANNOT
// rematerialize it from memory inside the loop (the VGPR=68/88 builds were
// re-loading imat from L2 every timestep — ~16 loads/thread/step on the
// critical path).
#define GLOAD16(dst, ptr)                                                         \
    asm volatile("global_load_dwordx4 %0, %1, off" : "=v"(dst) : "v"(ptr) : "memory")

// One block per batch element; h entirely in registers (4 elems/thread).
// Output identity: pinv([m|I]) @ [m|I] = I_20, so
//   y_t = 0.9*y_{t-1} + [krec*s_t ; kin*x_t],  s_t = n^T tanh(h_{t-1}).
__global__ __launch_bounds__(NTHREADS_, 1) void rnn_scan_kernel(
    const float* __restrict__ x,     // [B, T, 16]
    const float* __restrict__ m,     // [H, 4]
    const float* __restrict__ n,     // [H, 4]
    const float* __restrict__ imat,  // [H, 16]
    float* __restrict__ out)         // [B, T, 20]
{
    const int b    = blockIdx.x;
    const int tid  = threadIdx.x;
    const int wave = tid >> 6;
    const int lane = tid & 63;

    const float kd   = 0.9f;                      // 1 - ALPHA
    const float krec = 0.1f * (500.0f / 1024.0f); // ALPHA * BASE_SCALE / HIDDEN
    const float kin  = 0.1f;                      // ALPHA

    // ---- force-resident weight loads (opaque asm, non-rematerializable) ----
    f32x4 Iv[EPT_][4];
    f32x4 mv[EPT_];
    f32x4 nv[EPT_];
#pragma unroll
    for (int j = 0; j < EPT_; ++j) {
        const int hidx = tid * EPT_ + j;
        const float* ip = imat + hidx * INPUT_;
        GLOAD16(Iv[j][0], ip);
        GLOAD16(Iv[j][1], ip + 4);
        GLOAD16(Iv[j][2], ip + 8);
        GLOAD16(Iv[j][3], ip + 12);
        GLOAD16(mv[j], m + hidx * RANK_);
        GLOAD16(nv[j], n + hidx * RANK_);
    }
    asm volatile("s_waitcnt vmcnt(0)" ::: "memory");

    float h[EPT_];
    float mrs[EPT_][RANK_];    // krec * m row
    float nr[EPT_][RANK_];
    float Irs[EPT_][INPUT_];   // kin * I row
#pragma unroll
    for (int j = 0; j < EPT_; ++j) {
        h[j] = 0.0f;
#pragma unroll
        for (int r = 0; r < RANK_; ++r) {
            mrs[j][r] = krec * mv[j][r];
            nr[j][r]  = nv[j][r];
        }
#pragma unroll
        for (int q = 0; q < 4; ++q) {
#pragma unroll
            for (int e = 0; e < 4; ++e)
                Irs[j][q * 4 + e] = kin * Iv[j][q][e];
        }
    }

    // ---- LDS: cross-wave partials (parity dbuf) + staged x chunks (dbuf) ----
    __shared__ float4 part[2][NWAVES_];
    __shared__ float xs[2][CH_ * INPUT_];   // 2 x 4KB

    const float* xb = x + (size_t)b * T_ * INPUT_;
    float* ob = out + (size_t)b * T_ * (RANK_ + INPUT_);

    // Prologue staging: chunk 0 -> xs[0]; chunk 1 preloaded into xstage regs.
    // (visibility of xs[0] to all waves is guaranteed by the t=0 barrier's
    //  lgkmcnt(0): each wave drains its own write before passing it)
    {
        float4 c0 = *(const float4*)(xb + tid * 4);           // 256*16B = 4KB
        *(float4*)&xs[0][tid * 4] = c0;
    }
    float4 xstage = *(const float4*)(xb + CH_ * INPUT_ + tid * 4);

    float y = 0.0f;  // output accumulator (tid < 20)
    const int yoff = (tid >= 4 && tid < 20) ? (tid - 4) : 0;

    for (int t = 0; t < T_; ++t) {
        // --- tanh(h) + rank partials (VALU only) ---
        float th[EPT_];
#pragma unroll
        for (int j = 0; j < EPT_; ++j) th[j] = tanh_fast(h[j]);

        float p0 = th[0] * nr[0][0], p1 = th[0] * nr[0][1];
        float p2 = th[0] * nr[0][2], p3 = th[0] * nr[0][3];
#pragma unroll
        for (int j = 1; j < EPT_; ++j) {
            p0 = fmaf(th[j], nr[j][0], p0);
            p1 = fmaf(th[j], nr[j][1], p1);
            p2 = fmaf(th[j], nr[j][2], p2);
            p3 = fmaf(th[j], nr[j][3], p3);
        }

        // --- wave reduce via DPP, level-major for ILP across 4 ranks ---
        DPP_ADD(p0, 0x111); DPP_ADD(p1, 0x111); DPP_ADD(p2, 0x111); DPP_ADD(p3, 0x111);
        DPP_ADD(p0, 0x112); DPP_ADD(p1, 0x112); DPP_ADD(p2, 0x112); DPP_ADD(p3, 0x112);
        DPP_ADD(p0, 0x114); DPP_ADD(p1, 0x114); DPP_ADD(p2, 0x114); DPP_ADD(p3, 0x114);
        DPP_ADD(p0, 0x118); DPP_ADD(p1, 0x118); DPP_ADD(p2, 0x118); DPP_ADD(p3, 0x118);
        DPP_ADD(p0, 0x142); DPP_ADD(p1, 0x142); DPP_ADD(p2, 0x142); DPP_ADD(p3, 0x142);
        DPP_ADD(p0, 0x143); DPP_ADD(p1, 0x143); DPP_ADD(p2, 0x143); DPP_ADD(p3, 0x143);

        if (lane == 63) part[t & 1][wave] = make_float4(p0, p1, p2, p3);

        // Raw barrier: LDS-visibility wait ONLY (no vmcnt drain — x staging
        // loads and y stores stay in flight across steps).
        asm volatile("s_waitcnt lgkmcnt(0)\n\ts_barrier" ::: "memory");

        // --- chunk staging (post-barrier: xs[(c+1)&1]'s old data was last
        //     read pre-barrier, drained by that barrier's lgkmcnt(0)) ---
        if ((t & (CH_ - 1)) == 0) {
            const int c = t >> 6;
            *(float4*)&xs[(c + 1) & 1][tid * 4] = xstage;   // chunk c+1
            const int cl = (c + 2 < NCH_) ? (c + 2) : (NCH_ - 1);
            xstage = *(const float4*)(xb + cl * CH_ * INPUT_ + tid * 4);
        }

        // --- issue x_t reads (LDS broadcast), then cross-wave partials ---
        const float* xsp = &xs[(t >> 6) & 1][(t & 63) * INPUT_];
        const float4 xa = ((const float4*)xsp)[0];
        const float4 xbv = ((const float4*)xsp)[1];
        const float4 xc = ((const float4*)xsp)[2];
        const float4 xd = ((const float4*)xsp)[3];
        const float xyv = xsp[yoff];

        const float4 q0 = part[t & 1][0];
        const float4 q1 = part[t & 1][1];
        const float4 q2 = part[t & 1][2];
        const float4 q3 = part[t & 1][3];

        // --- ax = (kin*I) @ x_t : fills the ds_read latency window ---
        float ax[EPT_];
#pragma unroll
        for (int j = 0; j < EPT_; ++j) {
            float a = xa.x * Irs[j][0];
            float c = xa.y * Irs[j][1];
            a = fmaf(xa.z, Irs[j][2], a);   c = fmaf(xa.w, Irs[j][3], c);
            a = fmaf(xbv.x, Irs[j][4], a);  c = fmaf(xbv.y, Irs[j][5], c);
            a = fmaf(xbv.z, Irs[j][6], a);  c = fmaf(xbv.w, Irs[j][7], c);
            a = fmaf(xc.x, Irs[j][8], a);   c = fmaf(xc.y, Irs[j][9], c);
            a = fmaf(xc.z, Irs[j][10], a);  c = fmaf(xc.w, Irs[j][11], c);
            a = fmaf(xd.x, Irs[j][12], a);  c = fmaf(xd.y, Irs[j][13], c);
            a = fmaf(xd.z, Irs[j][14], a);  c = fmaf(xd.w, Irs[j][15], c);
            ax[j] = a + c;
        }

        // --- combine partials -> s ---
        const float s0 = (q0.x + q1.x) + (q2.x + q3.x);
        const float s1 = (q0.y + q1.y) + (q2.y + q3.y);
        const float s2 = (q0.z + q1.z) + (q2.z + q3.z);
        const float s3 = (q0.w + q1.w) + (q2.w + q3.w);

        // --- h <- kd*h + mrs@s + ax  (tree: ~16cy from s) ---
#pragma unroll
        for (int j = 0; j < EPT_; ++j) {
            float a01 = fmaf(s1, mrs[j][1], fmaf(s0, mrs[j][0], ax[j]));
            float a23 = fmaf(s3, mrs[j][3], s2 * mrs[j][2]);
            h[j] = fmaf(kd, h[j], a01 + a23);
        }

        // --- y_t = kd*y_{t-1} + [krec*s ; kin*x_t]  (lanes 0..19 of wave 0) ---
        if (tid < 20) {
            float drive;
            if (tid < 4) {
                float sv = (tid == 0) ? s0 : (tid == 1) ? s1 : (tid == 2) ? s2 : s3;
                drive = krec * sv;
            } else {
                drive = kin * xyv;
            }
            y = fmaf(kd, y, drive);
            ob[t * 20 + tid] = y;   // fire-and-forget: never drained in-loop
        }
    }
}

extern "C" void kernel_launch(void* const* d_in, const int* in_sizes, int n_in,
                              void* d_out, int out_size, void* d_ws, size_t ws_size,
                              hipStream_t stream) {
    const float* x    = (const float*)d_in[0];
    const float* m    = (const float*)d_in[1];
    const float* n    = (const float*)d_in[2];
    const float* imat = (const float*)d_in[3];
    float* out = (float*)d_out;

    rnn_scan_kernel<<<dim3(BATCH_), dim3(NTHREADS_), 0, stream>>>(x, m, n, imat, out);
}